// Round 17
// baseline (430.492 us; speedup 1.0000x reference)
//
#include <hip/hip_runtime.h>
#include <math.h>

#define N_ROWS 65536
#define K_CODES 4096
#define NTILES_TOTAL (K_CODES / 32)       // 128
#define K_CHUNKS 4
#define NTILES (NTILES_TOTAL / K_CHUNKS)  // 32 tiles per chunk
#define DIM 64
#define NBUF 2
#define ACC_MARGIN 0.15f    // acc-space; key-space 0.3 = 5.9 sigma of 2-term err-diff
#define RR 8                // rescore rows per codebook pass

typedef __attribute__((ext_vector_type(8))) short bf16x8;
typedef __attribute__((ext_vector_type(4))) float f32x4;

__device__ inline unsigned short f2bf_rne(float f) {
    unsigned u = __float_as_uint(f);
    return (unsigned short)((u + 0x7FFFu + ((u >> 16) & 1u)) >> 16);
}
__device__ inline float bf2f(unsigned short s) {
    return __uint_as_float(((unsigned)s) << 16);
}

// ---------------------------------------------------------------------------
// pack_e (unchanged, proven): hi/lo bf16 fragments, 16x16x32 layout.
// Frag f = ch*2+kh; lane l elem j <- e[tile*32+ch*16+(l&15)][kh*32+((l>>4)&3)*8+j].
// hi at tile*8KB + f*1KB, lo at +4KB. Also esq, esqn=-esq/2, count=0.
// ---------------------------------------------------------------------------
__global__ __launch_bounds__(256) void pack_e(const float* __restrict__ embed,
                                              short* __restrict__ e_pk,
                                              float* __restrict__ esq,
                                              float* __restrict__ esqn,
                                              int* __restrict__ count) {
    __shared__ float lds_f[2048];   // 32 codes x 64 dims
    const int tile = blockIdx.x;
    const int t = threadIdx.x;
    if (tile == 0 && t == 0) *count = 0;
    const float4* src = (const float4*)(embed + (size_t)tile * 2048);
    ((float4*)lds_f)[t] = src[t];
    ((float4*)lds_f)[t + 256] = src[t + 256];
    __syncthreads();
    const int l = t & 63;
    const int kh = (t >> 6) & 1;
    const int ch = (t >> 7) & 1;
    const int base = (ch * 16 + (l & 15)) * 64 + kh * 32 + ((l >> 4) & 3) * 8;
    bf16x8 vh, vl;
#pragma unroll
    for (int j = 0; j < 8; ++j) {
        float v = lds_f[base + j];
        unsigned short h = f2bf_rne(v);
        vh[j] = (short)h;
        vl[j] = (short)f2bf_rne(v - bf2f(h));
    }
    *(bf16x8*)(e_pk + (size_t)tile * 4096 + t * 8) = vh;
    *(bf16x8*)(e_pk + (size_t)tile * 4096 + 2048 + t * 8) = vl;
    if (t < 32) {
        float s = 0.f;
#pragma unroll
        for (int d = 0; d < 64; ++d) { float v = lds_f[t * 64 + d]; s = fmaf(v, v, s); }
        esq[tile * 32 + t] = s;
        esqn[tile * 32 + t] = -0.5f * s;
    }
}

// ---------------------------------------------------------------------------
// vq_main: R14's proven structure, 2-TERM: A = x rounded once (ah only);
// per tile 16 MFMA (ah.bh + ah.bl over 2 kh, 4 quadrants). wave = 32 rows;
// block = 128 rows; one K-chunk (32 tiles); grid 2048 = 8 blocks/CU.
// NBUF=2, one barrier/tile with full drain; stage(t+1) after barrier.
// ---------------------------------------------------------------------------
__global__ __launch_bounds__(256, 4) void vq_main(const float* __restrict__ x,
                                                  const short* __restrict__ e_pk,
                                                  const float* __restrict__ esqn,
                                                  float* __restrict__ b1s,
                                                  float* __restrict__ b2s,
                                                  int* __restrict__ i1s) {
    __shared__ __align__(16) char lds[NBUF][8192];   // [hi 4KB][lo 4KB] per slot
    __shared__ __align__(16) float lds_q[NBUF][64];  // staged esqn per slot
    const int tid = threadIdx.x;
    const int wid = tid >> 6;
    const int l = tid & 63;
    const int c16 = l & 15;          // fragment col index
    const int rgrp = (l >> 4) & 3;   // k-group / D-row-group selector
    const int kc = blockIdx.x & (K_CHUNKS - 1);
    const int rg = blockIdx.x >> 2;  // log2(K_CHUNKS)
    const int rowbase = rg * 128 + wid * 32;
    const int tile0 = kc * NTILES;

    // A fragments: x rounded ONCE to bf16 (2-term: error absorbed by margin).
    bf16x8 ah[2][2];   // [rh][kh]
#pragma unroll
    for (int rh = 0; rh < 2; ++rh) {
        const float* xr = x + (size_t)(rowbase + rh * 16 + c16) * DIM;
#pragma unroll
        for (int kh = 0; kh < 2; ++kh) {
            const float* p = xr + kh * 32 + rgrp * 8;
#pragma unroll
            for (int j = 0; j < 8; ++j)
                ah[rh][kh][j] = (short)f2bf_rne(p[j]);
        }
    }

    // Per-row trackers: slot e = rh*4 + j  (8 rows this lane contributes to).
    float b1[8], b2[8];
    int i1[8];
#pragma unroll
    for (int i = 0; i < 8; ++i) { b1[i] = -3.0e38f; b2[i] = -3.0e38f; i1[i] = 0; }

    // 3 VMEM ops per stage (hi 16B, lo 16B, esqn 4B).
    auto stage = [&](int t, int b) {
        const char* gsrc = (const char*)e_pk + (size_t)(tile0 + t) * 8192 + tid * 16;
        __builtin_amdgcn_global_load_lds(
            (const __attribute__((address_space(1))) void*)gsrc,
            (__attribute__((address_space(3))) void*)(&lds[b][wid * 1024]), 16, 0, 0);
        __builtin_amdgcn_global_load_lds(
            (const __attribute__((address_space(1))) void*)(gsrc + 4096),
            (__attribute__((address_space(3))) void*)(&lds[b][4096 + wid * 1024]), 16, 0, 0);
        const float* qsrc = esqn + (size_t)(tile0 + t) * 32 + l;
        __builtin_amdgcn_global_load_lds(
            (const __attribute__((address_space(1))) void*)qsrc,
            (__attribute__((address_space(3))) void*)(&lds_q[b][0]), 4, 0, 0);
    };

    stage(0, 0);

    for (int t = 0; t < NTILES; ++t) {
        const int cur = t & 1;
        asm volatile("s_waitcnt vmcnt(0) lgkmcnt(0)" ::: "memory");
        __builtin_amdgcn_sched_barrier(0);
        __builtin_amdgcn_s_barrier();
        __builtin_amdgcn_sched_barrier(0);
        if (t + 1 < NTILES) stage(t + 1, cur ^ 1);

        const float eq0 = lds_q[cur][c16];        // esqn, cols 0-15
        const float eq1 = lds_q[cur][16 + c16];   // esqn, cols 16-31
        const int ci0 = (tile0 + t) * 32 + c16;
        const int ci1 = ci0 + 16;

        // All 8 B fragments (hi+lo): frag f = ch*2+kh.
        bf16x8 bh[2][2], bl[2][2];
#pragma unroll
        for (int ch = 0; ch < 2; ++ch)
#pragma unroll
            for (int kh = 0; kh < 2; ++kh) {
                const int fo = ((ch * 2 + kh) * 64 + l) * 16;
                bh[ch][kh] = *(const bf16x8*)(&lds[cur][fo]);
                bl[ch][kh] = *(const bf16x8*)(&lds[cur][4096 + fo]);
            }

        // 4 quadrant accumulators (C-init = -e^2/2 of own cols).
        f32x4 a00 = {eq0, eq0, eq0, eq0};   // rh0, ch0
        f32x4 a01 = {eq1, eq1, eq1, eq1};   // rh0, ch1
        f32x4 a10 = {eq0, eq0, eq0, eq0};   // rh1, ch0
        f32x4 a11 = {eq1, eq1, eq1, eq1};   // rh1, ch1

        __builtin_amdgcn_s_setprio(1);
#pragma unroll
        for (int kh = 0; kh < 2; ++kh) {
            a00 = __builtin_amdgcn_mfma_f32_16x16x32_bf16(ah[0][kh], bh[0][kh], a00, 0, 0, 0);
            a01 = __builtin_amdgcn_mfma_f32_16x16x32_bf16(ah[0][kh], bh[1][kh], a01, 0, 0, 0);
            a10 = __builtin_amdgcn_mfma_f32_16x16x32_bf16(ah[1][kh], bh[0][kh], a10, 0, 0, 0);
            a11 = __builtin_amdgcn_mfma_f32_16x16x32_bf16(ah[1][kh], bh[1][kh], a11, 0, 0, 0);
            a00 = __builtin_amdgcn_mfma_f32_16x16x32_bf16(ah[0][kh], bl[0][kh], a00, 0, 0, 0);
            a01 = __builtin_amdgcn_mfma_f32_16x16x32_bf16(ah[0][kh], bl[1][kh], a01, 0, 0, 0);
            a10 = __builtin_amdgcn_mfma_f32_16x16x32_bf16(ah[1][kh], bl[0][kh], a10, 0, 0, 0);
            a11 = __builtin_amdgcn_mfma_f32_16x16x32_bf16(ah[1][kh], bl[1][kh], a11, 0, 0, 0);
        }
        __builtin_amdgcn_s_setprio(0);

        // Track per row: ch0 candidate then ch1 (ascending index -> first-min).
#define TRACK2(V0, V1, E)                                            \
        {                                                            \
            float v0 = (V0), v1 = (V1);                              \
            bool g0 = v0 > b1[E];                                    \
            b2[E] = __builtin_amdgcn_fmed3f(v0, b1[E], b2[E]);       \
            b1[E] = fmaxf(v0, b1[E]);                                \
            i1[E] = g0 ? ci0 : i1[E];                                \
            bool g1 = v1 > b1[E];                                    \
            b2[E] = __builtin_amdgcn_fmed3f(v1, b1[E], b2[E]);       \
            b1[E] = fmaxf(v1, b1[E]);                                \
            i1[E] = g1 ? ci1 : i1[E];                                \
        }
#pragma unroll
        for (int j = 0; j < 4; ++j) {
            TRACK2(a00[j], a01[j], j)
            TRACK2(a10[j], a11[j], 4 + j)
        }
#undef TRACK2
    }

    // Butterfly over the 16 col lanes (xor bits 0-3 preserve rgrp).
#pragma unroll
    for (int e = 0; e < 8; ++e) {
#pragma unroll
        for (int m = 1; m <= 8; m <<= 1) {
            float ob1 = __shfl_xor(b1[e], m);
            float ob2 = __shfl_xor(b2[e], m);
            int oi = __shfl_xor(i1[e], m);
            float nb2 = fmaxf(fminf(b1[e], ob1), fmaxf(b2[e], ob2));
            bool take = ob1 > b1[e];
            b1[e] = take ? ob1 : b1[e];
            i1[e] = take ? oi : i1[e];
            b2[e] = nb2;
        }
        if (c16 == 0) {
            int row = rowbase + (e >> 2) * 16 + rgrp * 4 + (e & 3);  // m89 D-row map
            b1s[(size_t)kc * N_ROWS + row] = b1[e];
            b2s[(size_t)kc * N_ROWS + row] = b2[e];
            i1s[(size_t)kc * N_ROWS + row] = i1[e];
        }
    }
}

// ---------------------------------------------------------------------------
// vq_merge_gather: merge K_CHUNKS chunks per row (ascending, strict >),
// flag gap < ACC_MARGIN, write out_ind + out_q (8 threads per row).
// ---------------------------------------------------------------------------
__global__ __launch_bounds__(256) void vq_merge_gather(const float* __restrict__ embed,
                                                       const float* __restrict__ b1s,
                                                       const float* __restrict__ b2s,
                                                       const int* __restrict__ i1s,
                                                       float* __restrict__ out_q,
                                                       float* __restrict__ out_ind,
                                                       int* __restrict__ list,
                                                       int* __restrict__ count) {
    int t = blockIdx.x * 256 + threadIdx.x;
    int r = t >> 3, q = t & 7;
    float m1 = b1s[r];
    float m2 = b2s[r];
    int idx = i1s[r];
#pragma unroll
    for (int c = 1; c < K_CHUNKS; ++c) {
        float c1 = b1s[(size_t)c * N_ROWS + r];
        float c2 = b2s[(size_t)c * N_ROWS + r];
        int ci = i1s[(size_t)c * N_ROWS + r];
        bool take = c1 > m1;
        m2 = fmaxf(fminf(m1, c1), fmaxf(m2, c2));   // union second-best
        m1 = fmaxf(m1, c1);
        idx = take ? ci : idx;
    }
    const float4* src = (const float4*)(embed + (size_t)idx * DIM + q * 8);
    float4* dst = (float4*)(out_q + (size_t)r * DIM + q * 8);
    dst[0] = src[0];
    dst[1] = src[1];
    if (q == 0) {
        out_ind[r] = (float)idx;
        if (m1 - m2 < ACC_MARGIN) {
            int p = atomicAdd(count, 1);
            list[p] = r;
        }
    }
}

// ---------------------------------------------------------------------------
// vq_rescore: exact fp32 rescan, RR rows per codebook pass (L2 traffic / RR).
// Patches out directly. Lexicographic (key, idx) == numpy first-min.
// ---------------------------------------------------------------------------
__global__ __launch_bounds__(256) void vq_rescore(const float* __restrict__ x,
                                                  const float* __restrict__ embed,
                                                  const float* __restrict__ esq,
                                                  const int* __restrict__ list,
                                                  const int* __restrict__ count,
                                                  float* __restrict__ out_q,
                                                  float* __restrict__ out_ind) {
    __shared__ float xs[RR][64];
    __shared__ int rowids[RR];
    __shared__ float sk[256];
    __shared__ int si[256];
    const int tid = threadIdx.x;
    const int n = *count;
    for (int base = blockIdx.x * RR; base < n; base += gridDim.x * RR) {
        const int nr = min(RR, n - base);
        __syncthreads();   // protect previous iteration's xs/rowids readers
        if (tid < nr) rowids[tid] = list[base + tid];
        __syncthreads();
        if (tid < nr * 16) {
            int r = tid >> 4, q = tid & 15;
            ((float4*)xs[r])[q] = ((const float4*)(x + (size_t)rowids[r] * DIM))[q];
        }
        __syncthreads();

        float best[RR];
        int bi[RR];
#pragma unroll
        for (int r = 0; r < RR; ++r) { best[r] = 3.0e38f; bi[r] = 0; }

        for (int i = 0; i < 16; ++i) {
            const int c = tid + (i << 8);
            const float4* e4 = (const float4*)(embed + (size_t)c * DIM);
            float dot[RR];
#pragma unroll
            for (int r = 0; r < RR; ++r) dot[r] = 0.f;
#pragma unroll
            for (int q = 0; q < 16; ++q) {
                float4 ev = e4[q];
#pragma unroll
                for (int r = 0; r < RR; ++r) {
                    float4 xv = ((const float4*)xs[r])[q];   // LDS b128 broadcast
                    dot[r] = fmaf(xv.x, ev.x, dot[r]);
                    dot[r] = fmaf(xv.y, ev.y, dot[r]);
                    dot[r] = fmaf(xv.z, ev.z, dot[r]);
                    dot[r] = fmaf(xv.w, ev.w, dot[r]);
                }
            }
            const float eq = esq[c];
#pragma unroll
            for (int r = 0; r < RR; ++r) {
                float key = fmaf(-2.f, dot[r], eq);
                if (key < best[r]) { best[r] = key; bi[r] = c; }  // c ascending in-thread
            }
        }

        for (int r = 0; r < nr; ++r) {
            sk[tid] = best[r];
            si[tid] = bi[r];
            __syncthreads();
            for (int s = 128; s > 0; s >>= 1) {
                if (tid < s) {
                    float ok = sk[tid + s]; int oi = si[tid + s];
                    if (ok < sk[tid] || (ok == sk[tid] && oi < si[tid])) { sk[tid] = ok; si[tid] = oi; }
                }
                __syncthreads();
            }
            if (tid == 0) out_ind[rowids[r]] = (float)si[0];
            if (tid < 16) {
                ((float4*)(out_q + (size_t)rowids[r] * DIM))[tid] =
                    ((const float4*)(embed + (size_t)si[0] * DIM))[tid];
            }
            __syncthreads();
        }
    }
}

// ---------------------------------------------------------------------------
extern "C" void kernel_launch(void* const* d_in, const int* in_sizes, int n_in,
                              void* d_out, int out_size, void* d_ws, size_t ws_size,
                              hipStream_t stream) {
    const float* x = (const float*)d_in[0];      // [N, D] fp32
    const float* embed = (const float*)d_in[1];  // [1, K, D] fp32
    float* out = (float*)d_out;                  // [N*D quantize][N indices]
    float* out_ind = out + (size_t)N_ROWS * DIM;

    char* ws = (char*)d_ws;
    short* e_pk = (short*)ws;                            // 1 MB
    size_t off = 1 << 20;
    float* esq = (float*)(ws + off);  off += 17 << 10;   // 16 KB (+pad)
    float* esqn = (float*)(ws + off); off += 17 << 10;   // 16 KB + stage pad
    float* b1s = (float*)(ws + off);  off += (size_t)K_CHUNKS * N_ROWS * 4;
    float* b2s = (float*)(ws + off);  off += (size_t)K_CHUNKS * N_ROWS * 4;
    int* i1s = (int*)(ws + off);      off += (size_t)K_CHUNKS * N_ROWS * 4;
    int* list = (int*)(ws + off);     off += (size_t)N_ROWS * 4;
    int* count = (int*)(ws + off);

    pack_e<<<NTILES_TOTAL, 256, 0, stream>>>(embed, e_pk, esq, esqn, count);
    vq_main<<<(N_ROWS / 128) * K_CHUNKS, 256, 0, stream>>>(x, e_pk, esqn, b1s, b2s, i1s);
    vq_merge_gather<<<N_ROWS * 8 / 256, 256, 0, stream>>>(embed, b1s, b2s, i1s,
                                                          out, out_ind, list, count);
    vq_rescore<<<2048, 256, 0, stream>>>(x, embed, esq, list, count, out, out_ind);
}

// Round 18
// 428.036 us; speedup vs baseline: 1.0057x; 1.0057x over previous
//
#include <hip/hip_runtime.h>
#include <math.h>

#define N_ROWS 65536
#define K_CODES 4096
#define NTILES_TOTAL (K_CODES / 32)       // 128
#define K_CHUNKS 4
#define NTILES (NTILES_TOTAL / K_CHUNKS)  // 32 tiles per chunk
#define DIM 64
#define NBUF 2
#define ACC_MARGIN 0.15f    // acc-space; key-space 0.3 = 5.9 sigma of 2-term err-diff
#define RR 8                // rescore rows per codebook pass

typedef __attribute__((ext_vector_type(8))) short bf16x8;
typedef __attribute__((ext_vector_type(4))) float f32x4;

__device__ inline unsigned short f2bf_rne(float f) {
    unsigned u = __float_as_uint(f);
    return (unsigned short)((u + 0x7FFFu + ((u >> 16) & 1u)) >> 16);
}
__device__ inline float bf2f(unsigned short s) {
    return __uint_as_float(((unsigned)s) << 16);
}

// ---------------------------------------------------------------------------
// pack_e (unchanged, proven): hi/lo bf16 fragments, 16x16x32 layout.
// ---------------------------------------------------------------------------
__global__ __launch_bounds__(256) void pack_e(const float* __restrict__ embed,
                                              short* __restrict__ e_pk,
                                              float* __restrict__ esq,
                                              float* __restrict__ esqn,
                                              int* __restrict__ count) {
    __shared__ float lds_f[2048];   // 32 codes x 64 dims
    const int tile = blockIdx.x;
    const int t = threadIdx.x;
    if (tile == 0 && t == 0) *count = 0;
    const float4* src = (const float4*)(embed + (size_t)tile * 2048);
    ((float4*)lds_f)[t] = src[t];
    ((float4*)lds_f)[t + 256] = src[t + 256];
    __syncthreads();
    const int l = t & 63;
    const int kh = (t >> 6) & 1;
    const int ch = (t >> 7) & 1;
    const int base = (ch * 16 + (l & 15)) * 64 + kh * 32 + ((l >> 4) & 3) * 8;
    bf16x8 vh, vl;
#pragma unroll
    for (int j = 0; j < 8; ++j) {
        float v = lds_f[base + j];
        unsigned short h = f2bf_rne(v);
        vh[j] = (short)h;
        vl[j] = (short)f2bf_rne(v - bf2f(h));
    }
    *(bf16x8*)(e_pk + (size_t)tile * 4096 + t * 8) = vh;
    *(bf16x8*)(e_pk + (size_t)tile * 4096 + 2048 + t * 8) = vl;
    if (t < 32) {
        float s = 0.f;
#pragma unroll
        for (int d = 0; d < 64; ++d) { float v = lds_f[t * 64 + d]; s = fmaf(v, v, s); }
        esq[tile * 32 + t] = s;
        esqn[tile * 32 + t] = -0.5f * s;
    }
}

// ---------------------------------------------------------------------------
// vq_main (unchanged from R17): 2-term, 16 MFMA/tile, 8 blocks/CU.
// ---------------------------------------------------------------------------
__global__ __launch_bounds__(256, 4) void vq_main(const float* __restrict__ x,
                                                  const short* __restrict__ e_pk,
                                                  const float* __restrict__ esqn,
                                                  float* __restrict__ b1s,
                                                  float* __restrict__ b2s,
                                                  int* __restrict__ i1s) {
    __shared__ __align__(16) char lds[NBUF][8192];   // [hi 4KB][lo 4KB] per slot
    __shared__ __align__(16) float lds_q[NBUF][64];  // staged esqn per slot
    const int tid = threadIdx.x;
    const int wid = tid >> 6;
    const int l = tid & 63;
    const int c16 = l & 15;
    const int rgrp = (l >> 4) & 3;
    const int kc = blockIdx.x & (K_CHUNKS - 1);
    const int rg = blockIdx.x >> 2;
    const int rowbase = rg * 128 + wid * 32;
    const int tile0 = kc * NTILES;

    // A fragments: x rounded ONCE to bf16 (2-term; error absorbed by margin).
    bf16x8 ah[2][2];   // [rh][kh]
#pragma unroll
    for (int rh = 0; rh < 2; ++rh) {
        const float* xr = x + (size_t)(rowbase + rh * 16 + c16) * DIM;
#pragma unroll
        for (int kh = 0; kh < 2; ++kh) {
            const float* p = xr + kh * 32 + rgrp * 8;
#pragma unroll
            for (int j = 0; j < 8; ++j)
                ah[rh][kh][j] = (short)f2bf_rne(p[j]);
        }
    }

    float b1[8], b2[8];
    int i1[8];
#pragma unroll
    for (int i = 0; i < 8; ++i) { b1[i] = -3.0e38f; b2[i] = -3.0e38f; i1[i] = 0; }

    auto stage = [&](int t, int b) {
        const char* gsrc = (const char*)e_pk + (size_t)(tile0 + t) * 8192 + tid * 16;
        __builtin_amdgcn_global_load_lds(
            (const __attribute__((address_space(1))) void*)gsrc,
            (__attribute__((address_space(3))) void*)(&lds[b][wid * 1024]), 16, 0, 0);
        __builtin_amdgcn_global_load_lds(
            (const __attribute__((address_space(1))) void*)(gsrc + 4096),
            (__attribute__((address_space(3))) void*)(&lds[b][4096 + wid * 1024]), 16, 0, 0);
        const float* qsrc = esqn + (size_t)(tile0 + t) * 32 + l;
        __builtin_amdgcn_global_load_lds(
            (const __attribute__((address_space(1))) void*)qsrc,
            (__attribute__((address_space(3))) void*)(&lds_q[b][0]), 4, 0, 0);
    };

    stage(0, 0);

    for (int t = 0; t < NTILES; ++t) {
        const int cur = t & 1;
        asm volatile("s_waitcnt vmcnt(0) lgkmcnt(0)" ::: "memory");
        __builtin_amdgcn_sched_barrier(0);
        __builtin_amdgcn_s_barrier();
        __builtin_amdgcn_sched_barrier(0);
        if (t + 1 < NTILES) stage(t + 1, cur ^ 1);

        const float eq0 = lds_q[cur][c16];
        const float eq1 = lds_q[cur][16 + c16];
        const int ci0 = (tile0 + t) * 32 + c16;
        const int ci1 = ci0 + 16;

        bf16x8 bh[2][2], bl[2][2];
#pragma unroll
        for (int ch = 0; ch < 2; ++ch)
#pragma unroll
            for (int kh = 0; kh < 2; ++kh) {
                const int fo = ((ch * 2 + kh) * 64 + l) * 16;
                bh[ch][kh] = *(const bf16x8*)(&lds[cur][fo]);
                bl[ch][kh] = *(const bf16x8*)(&lds[cur][4096 + fo]);
            }

        f32x4 a00 = {eq0, eq0, eq0, eq0};
        f32x4 a01 = {eq1, eq1, eq1, eq1};
        f32x4 a10 = {eq0, eq0, eq0, eq0};
        f32x4 a11 = {eq1, eq1, eq1, eq1};

        __builtin_amdgcn_s_setprio(1);
#pragma unroll
        for (int kh = 0; kh < 2; ++kh) {
            a00 = __builtin_amdgcn_mfma_f32_16x16x32_bf16(ah[0][kh], bh[0][kh], a00, 0, 0, 0);
            a01 = __builtin_amdgcn_mfma_f32_16x16x32_bf16(ah[0][kh], bh[1][kh], a01, 0, 0, 0);
            a10 = __builtin_amdgcn_mfma_f32_16x16x32_bf16(ah[1][kh], bh[0][kh], a10, 0, 0, 0);
            a11 = __builtin_amdgcn_mfma_f32_16x16x32_bf16(ah[1][kh], bh[1][kh], a11, 0, 0, 0);
            a00 = __builtin_amdgcn_mfma_f32_16x16x32_bf16(ah[0][kh], bl[0][kh], a00, 0, 0, 0);
            a01 = __builtin_amdgcn_mfma_f32_16x16x32_bf16(ah[0][kh], bl[1][kh], a01, 0, 0, 0);
            a10 = __builtin_amdgcn_mfma_f32_16x16x32_bf16(ah[1][kh], bl[0][kh], a10, 0, 0, 0);
            a11 = __builtin_amdgcn_mfma_f32_16x16x32_bf16(ah[1][kh], bl[1][kh], a11, 0, 0, 0);
        }
        __builtin_amdgcn_s_setprio(0);

#define TRACK2(V0, V1, E)                                            \
        {                                                            \
            float v0 = (V0), v1 = (V1);                              \
            bool g0 = v0 > b1[E];                                    \
            b2[E] = __builtin_amdgcn_fmed3f(v0, b1[E], b2[E]);       \
            b1[E] = fmaxf(v0, b1[E]);                                \
            i1[E] = g0 ? ci0 : i1[E];                                \
            bool g1 = v1 > b1[E];                                    \
            b2[E] = __builtin_amdgcn_fmed3f(v1, b1[E], b2[E]);       \
            b1[E] = fmaxf(v1, b1[E]);                                \
            i1[E] = g1 ? ci1 : i1[E];                                \
        }
#pragma unroll
        for (int j = 0; j < 4; ++j) {
            TRACK2(a00[j], a01[j], j)
            TRACK2(a10[j], a11[j], 4 + j)
        }
#undef TRACK2
    }

#pragma unroll
    for (int e = 0; e < 8; ++e) {
#pragma unroll
        for (int m = 1; m <= 8; m <<= 1) {
            float ob1 = __shfl_xor(b1[e], m);
            float ob2 = __shfl_xor(b2[e], m);
            int oi = __shfl_xor(i1[e], m);
            float nb2 = fmaxf(fminf(b1[e], ob1), fmaxf(b2[e], ob2));
            bool take = ob1 > b1[e];
            b1[e] = take ? ob1 : b1[e];
            i1[e] = take ? oi : i1[e];
            b2[e] = nb2;
        }
        if (c16 == 0) {
            int row = rowbase + (e >> 2) * 16 + rgrp * 4 + (e & 3);
            b1s[(size_t)kc * N_ROWS + row] = b1[e];
            b2s[(size_t)kc * N_ROWS + row] = b2[e];
            i1s[(size_t)kc * N_ROWS + row] = i1[e];
        }
    }
}

// ---------------------------------------------------------------------------
// vq_merge_gather (unchanged): merge chunks, flag gap < ACC_MARGIN.
// ---------------------------------------------------------------------------
__global__ __launch_bounds__(256) void vq_merge_gather(const float* __restrict__ embed,
                                                       const float* __restrict__ b1s,
                                                       const float* __restrict__ b2s,
                                                       const int* __restrict__ i1s,
                                                       float* __restrict__ out_q,
                                                       float* __restrict__ out_ind,
                                                       int* __restrict__ list,
                                                       int* __restrict__ count) {
    int t = blockIdx.x * 256 + threadIdx.x;
    int r = t >> 3, q = t & 7;
    float m1 = b1s[r];
    float m2 = b2s[r];
    int idx = i1s[r];
#pragma unroll
    for (int c = 1; c < K_CHUNKS; ++c) {
        float c1 = b1s[(size_t)c * N_ROWS + r];
        float c2 = b2s[(size_t)c * N_ROWS + r];
        int ci = i1s[(size_t)c * N_ROWS + r];
        bool take = c1 > m1;
        m2 = fmaxf(fminf(m1, c1), fmaxf(m2, c2));   // union second-best
        m1 = fmaxf(m1, c1);
        idx = take ? ci : idx;
    }
    const float4* src = (const float4*)(embed + (size_t)idx * DIM + q * 8);
    float4* dst = (float4*)(out_q + (size_t)r * DIM + q * 8);
    dst[0] = src[0];
    dst[1] = src[1];
    if (q == 0) {
        out_ind[r] = (float)idx;
        if (m1 - m2 < ACC_MARGIN) {
            int p = atomicAdd(count, 1);
            list[p] = r;
        }
    }
}

// ---------------------------------------------------------------------------
// vq_rescore: exact fp32 rescan, RR rows per codebook pass.
// FIX vs R17: merge phase fully unrolled with STATIC index (rule #20) --
// runtime-r indexing of best[]/bi[] had spilled everything to scratch
// (VGPR 256, 53 MB writes, 322 us). nr is block-uniform -> break is safe.
// ---------------------------------------------------------------------------
__global__ __launch_bounds__(256) void vq_rescore(const float* __restrict__ x,
                                                  const float* __restrict__ embed,
                                                  const float* __restrict__ esq,
                                                  const int* __restrict__ list,
                                                  const int* __restrict__ count,
                                                  float* __restrict__ out_q,
                                                  float* __restrict__ out_ind) {
    __shared__ float xs[RR][64];
    __shared__ int rowids[RR];
    __shared__ float sk[256];
    __shared__ int si[256];
    const int tid = threadIdx.x;
    const int n = *count;
    for (int base = blockIdx.x * RR; base < n; base += gridDim.x * RR) {
        const int nr = min(RR, n - base);      // block-uniform
        __syncthreads();   // protect previous iteration's xs/rowids readers
        if (tid < nr) rowids[tid] = list[base + tid];
        __syncthreads();
        if (tid < nr * 16) {
            int r = tid >> 4, q = tid & 15;
            ((float4*)xs[r])[q] = ((const float4*)(x + (size_t)rowids[r] * DIM))[q];
        }
        __syncthreads();

        float best[RR];
        int bi[RR];
#pragma unroll
        for (int r = 0; r < RR; ++r) { best[r] = 3.0e38f; bi[r] = 0; }

        for (int i = 0; i < 16; ++i) {
            const int c = tid + (i << 8);
            const float4* e4 = (const float4*)(embed + (size_t)c * DIM);
            float dot[RR];
#pragma unroll
            for (int r = 0; r < RR; ++r) dot[r] = 0.f;
#pragma unroll
            for (int q = 0; q < 16; ++q) {
                float4 ev = e4[q];
#pragma unroll
                for (int r = 0; r < RR; ++r) {
                    float4 xv = ((const float4*)xs[r])[q];   // LDS b128 broadcast
                    dot[r] = fmaf(xv.x, ev.x, dot[r]);
                    dot[r] = fmaf(xv.y, ev.y, dot[r]);
                    dot[r] = fmaf(xv.z, ev.z, dot[r]);
                    dot[r] = fmaf(xv.w, ev.w, dot[r]);
                }
            }
            const float eq = esq[c];
#pragma unroll
            for (int r = 0; r < RR; ++r) {
                float key = fmaf(-2.f, dot[r], eq);
                if (key < best[r]) { best[r] = key; bi[r] = c; }  // c ascending in-thread
            }
        }

        // Merge: compile-time r (static best[r]/bi[r] index), uniform break.
#pragma unroll
        for (int r = 0; r < RR; ++r) {
            if (r >= nr) break;                 // nr block-uniform -> no divergence
            sk[tid] = best[r];
            si[tid] = bi[r];
            __syncthreads();
            for (int s = 128; s > 0; s >>= 1) {
                if (tid < s) {
                    float ok = sk[tid + s]; int oi = si[tid + s];
                    if (ok < sk[tid] || (ok == sk[tid] && oi < si[tid])) { sk[tid] = ok; si[tid] = oi; }
                }
                __syncthreads();
            }
            if (tid == 0) out_ind[rowids[r]] = (float)si[0];
            if (tid < 16) {
                ((float4*)(out_q + (size_t)rowids[r] * DIM))[tid] =
                    ((const float4*)(embed + (size_t)si[0] * DIM))[tid];
            }
            __syncthreads();
        }
    }
}

// ---------------------------------------------------------------------------
extern "C" void kernel_launch(void* const* d_in, const int* in_sizes, int n_in,
                              void* d_out, int out_size, void* d_ws, size_t ws_size,
                              hipStream_t stream) {
    const float* x = (const float*)d_in[0];      // [N, D] fp32
    const float* embed = (const float*)d_in[1];  // [1, K, D] fp32
    float* out = (float*)d_out;                  // [N*D quantize][N indices]
    float* out_ind = out + (size_t)N_ROWS * DIM;

    char* ws = (char*)d_ws;
    short* e_pk = (short*)ws;                            // 1 MB
    size_t off = 1 << 20;
    float* esq = (float*)(ws + off);  off += 17 << 10;   // 16 KB (+pad)
    float* esqn = (float*)(ws + off); off += 17 << 10;   // 16 KB + stage pad
    float* b1s = (float*)(ws + off);  off += (size_t)K_CHUNKS * N_ROWS * 4;
    float* b2s = (float*)(ws + off);  off += (size_t)K_CHUNKS * N_ROWS * 4;
    int* i1s = (int*)(ws + off);      off += (size_t)K_CHUNKS * N_ROWS * 4;
    int* list = (int*)(ws + off);     off += (size_t)N_ROWS * 4;
    int* count = (int*)(ws + off);

    pack_e<<<NTILES_TOTAL, 256, 0, stream>>>(embed, e_pk, esq, esqn, count);
    vq_main<<<(N_ROWS / 128) * K_CHUNKS, 256, 0, stream>>>(x, e_pk, esqn, b1s, b2s, i1s);
    vq_merge_gather<<<N_ROWS * 8 / 256, 256, 0, stream>>>(embed, b1s, b2s, i1s,
                                                          out, out_ind, list, count);
    vq_rescore<<<2048, 256, 0, stream>>>(x, embed, esq, list, count, out, out_ind);
}